// Round 3
// baseline (733.693 us; speedup 1.0000x reference)
//
#include <hip/hip_runtime.h>

// WindowAttention fused kernel for MI355X (gfx950). FP32 I/O.
// Shapes: B=4096, N=64, C=128, NH=4, HD=32, NW=2048.
// One block per batch; 4 waves = 4 heads; intermediates bf16 in LDS;
// fp32-sourced MFMA operands use hi/lo bf16 split (3-MFMA / 2-MFMA forms).

typedef unsigned short u16;
typedef __attribute__((ext_vector_type(8))) __bf16 bf16x8;
typedef __attribute__((ext_vector_type(4))) float f32x4;
typedef __attribute__((ext_vector_type(8))) float f32x8;

#define SCALE 0.17677669529663687f  // HD^-0.5, HD=32

__device__ __forceinline__ float b2f(u16 u) {
  union { float f; unsigned i; } x; x.i = ((unsigned)u) << 16; return x.f;
}
__device__ __forceinline__ u16 f2b(float f) {  // fp32 -> bf16 RNE
  unsigned u = __float_as_uint(f);
  u = u + 0x7FFFu + ((u >> 16) & 1u);
  return (u16)(u >> 16);
}
__device__ __forceinline__ bf16x8 ldb16(const u16* p) {   // LDS 16B vector load
  bf16x8 v; __builtin_memcpy(&v, (const void*)p, 16); return v;
}
__device__ __forceinline__ bf16x8 ldb8x2(const u16* p) {  // LDS 8B-aligned load
  bf16x8 v; __builtin_memcpy(&v, (const void*)p, 8);
  __builtin_memcpy((char*)&v + 8, (const void*)(p + 4), 8); return v;
}
__device__ __forceinline__ f32x8 ldf8(const float* p) {   // global 32B load
  f32x8 v; __builtin_memcpy(&v, (const void*)p, 32); return v;
}
// fp32x8 -> (hi, lo) bf16x8 pair; hi+lo reproduces f to ~2^-17 rel.
__device__ __forceinline__ void split8(const f32x8 f, bf16x8* h, bf16x8* l) {
#pragma unroll
  for (int j = 0; j < 8; ++j) {
    float fj = f[j];
    __bf16 hj = (__bf16)fj;
    (*h)[j] = hj;
    (*l)[j] = (__bf16)(fj - (float)hj);
  }
}

// LDS map (u16 units; 53248 B total -> 3 blocks/CU on 160KB):
//   v_s [4][32][72] @0      : v transposed, v_s[h][d][n]
//   k_s [4][64][40] @9216   : k_s[h][m][d]
//   p_s [4][64][68] @9216   : probs (aliases k_s, after barrier)
//   o_s [64][136]   @0      : out2 (aliases v_s, after barrier)
// Every LDS producer->consumer edge is __syncthreads()-ordered.

__global__ __launch_bounds__(256, 3) void wattn(
    const float* __restrict__ x, const float* __restrict__ y,
    const float* __restrict__ P, const float* __restrict__ msk,
    const float* __restrict__ qkvw, const float* __restrict__ qkvb,
    const float* __restrict__ projw, const float* __restrict__ projb,
    const float* __restrict__ lamp, float* __restrict__ out)
{
  __shared__ u16 sm[26624];
  u16* v_s = sm;
  u16* k_s = sm + 9216;
  u16* p_s = sm + 9216;
  u16* o_s = sm;

  const int b    = blockIdx.x;
  const int tid  = threadIdx.x;
  const int w    = tid >> 6;        // wave id == head id
  const int lane = tid & 63;
  const int q    = lane >> 4;       // quad
  const int r    = lane & 15;
  const float lam = lamp[0];
  const f32x4 zf = {0.f, 0.f, 0.f, 0.f};

  // ========== P1: kv = y @ qkv_w^T + qkv_b  (hi/lo bf16, 3-MFMA) ==========
  {
    const float* yb = y + (size_t)b * 8192;
#pragma unroll
    for (int hf = 0; hf < 2; ++hf) {      // two column halves (reg pressure)
      bf16x8 bwh[2][4], bwl[2][4];
      float bias[2];
#pragma unroll
      for (int c2 = 0; c2 < 2; ++c2) {
        int col = (w * 4 + hf * 2 + c2) * 16 + r;
        bias[c2] = qkvb[col];
#pragma unroll
        for (int ks = 0; ks < 4; ++ks) {
          f32x8 bw = ldf8(qkvw + col * 128 + ks * 32 + q * 8);
          split8(bw, &bwh[c2][ks], &bwl[c2][ks]);
        }
      }
#pragma unroll
      for (int nt = 0; nt < 4; ++nt) {
        bf16x8 ayh[4], ayl[4];
#pragma unroll
        for (int ks = 0; ks < 4; ++ks) {
          f32x8 ay = ldf8(yb + (nt * 16 + r) * 128 + ks * 32 + q * 8);
          split8(ay, &ayh[ks], &ayl[ks]);
        }
#pragma unroll
        for (int c2 = 0; c2 < 2; ++c2) {
          f32x4 acc = zf;
#pragma unroll
          for (int ks = 0; ks < 4; ++ks) {
            acc = __builtin_amdgcn_mfma_f32_16x16x32_bf16(ayh[ks], bwh[c2][ks], acc, 0, 0, 0);
            acc = __builtin_amdgcn_mfma_f32_16x16x32_bf16(ayh[ks], bwl[c2][ks], acc, 0, 0, 0);
            acc = __builtin_amdgcn_mfma_f32_16x16x32_bf16(ayl[ks], bwh[c2][ks], acc, 0, 0, 0);
          }
          int col = (w * 4 + hf * 2 + c2) * 16 + r;
#pragma unroll
          for (int i = 0; i < 4; ++i) {
            float val = acc[i] + bias[c2];
            int n = nt * 16 + q * 4 + i;         // C-layout: row=quad*4+i, col=r
            if (w < 2) {                          // cols 0..127 -> k
              int h_ = col >> 5, d = col & 31;
              k_s[(h_ * 64 + n) * 40 + d] = f2b(val);
            } else {                              // cols 128..255 -> v (transposed)
              int c3 = col - 128;
              int h_ = c3 >> 5, d = c3 & 31;
              v_s[(h_ * 32 + d) * 72 + n] = f2b(val);
            }
          }
        }
      }
    }
  }
  __syncthreads();  // B0: k_s/v_s visible

  // ===== P2: s = (x_q @ k^T)*SCALE + mask + lam*P ; in-register softmax =====
  f32x4 s[4][4];
  {
    const float* xq = x + (size_t)b * 8192 + w * 2048;  // q = reshape of x
    bf16x8 aqh[4], aql[4], bk[4];
#pragma unroll
    for (int nt = 0; nt < 4; ++nt) {
      f32x8 a = ldf8(xq + (nt * 16 + r) * 32 + q * 8);
      split8(a, &aqh[nt], &aql[nt]);
    }
#pragma unroll
    for (int mt = 0; mt < 4; ++mt)
      bk[mt] = ldb16(k_s + (w * 64 + mt * 16 + r) * 40 + q * 8);
#pragma unroll
    for (int nt = 0; nt < 4; ++nt)
#pragma unroll
      for (int mt = 0; mt < 4; ++mt) {
        f32x4 t = __builtin_amdgcn_mfma_f32_16x16x32_bf16(aqh[nt], bk[mt], zf, 0, 0, 0);
        s[nt][mt] = __builtin_amdgcn_mfma_f32_16x16x32_bf16(aql[nt], bk[mt], t, 0, 0, 0);
      }
  }
  __syncthreads();  // B1: k_s reads done; p_s (aliasing) may be written
  {
    const float* Pb = P + ((size_t)b * 4 + w) * 4096;
    const float* mb = msk + (size_t)(b & 2047) * 4096;
#pragma unroll
    for (int nt = 0; nt < 4; ++nt) {
#pragma unroll
      for (int i = 0; i < 4; ++i) {
        int n = nt * 16 + q * 4 + i;
        float sv[4];
#pragma unroll
        for (int mt = 0; mt < 4; ++mt) {
          int m = mt * 16 + r;
          sv[mt] = s[nt][mt][i] * SCALE + mb[n * 64 + m] + lam * Pb[n * 64 + m];
        }
        float mx = fmaxf(fmaxf(sv[0], sv[1]), fmaxf(sv[2], sv[3]));
        mx = fmaxf(mx, __shfl_xor(mx, 1));
        mx = fmaxf(mx, __shfl_xor(mx, 2));
        mx = fmaxf(mx, __shfl_xor(mx, 4));
        mx = fmaxf(mx, __shfl_xor(mx, 8));
        float e[4], sum = 0.f;
#pragma unroll
        for (int mt = 0; mt < 4; ++mt) { e[mt] = __expf(sv[mt] - mx); sum += e[mt]; }
        sum += __shfl_xor(sum, 1);
        sum += __shfl_xor(sum, 2);
        sum += __shfl_xor(sum, 4);
        sum += __shfl_xor(sum, 8);
        float inv = 1.0f / sum;
#pragma unroll
        for (int mt = 0; mt < 4; ++mt)
          p_s[(w * 64 + n) * 68 + mt * 16 + r] = f2b(e[mt] * inv);
      }
    }
  }
  __syncthreads();  // B1b: p_s stores ordered before P4 reads

  // ========== P4: out_h = p @ v  (p, v exact bf16 -> single MFMA) ==========
  f32x4 o[4][2];
  {
    bf16x8 bv[2][2];
#pragma unroll
    for (int dt = 0; dt < 2; ++dt)
#pragma unroll
      for (int ks = 0; ks < 2; ++ks)
        bv[dt][ks] = ldb16(v_s + (w * 32 + dt * 16 + r) * 72 + ks * 32 + q * 8);
#pragma unroll
    for (int nt = 0; nt < 4; ++nt) {
      bf16x8 ap[2];
#pragma unroll
      for (int ks = 0; ks < 2; ++ks)
        ap[ks] = ldb8x2(p_s + (w * 64 + nt * 16 + r) * 68 + ks * 32 + q * 8);
#pragma unroll
      for (int dt = 0; dt < 2; ++dt) {
        f32x4 t = zf;
        t = __builtin_amdgcn_mfma_f32_16x16x32_bf16(ap[0], bv[dt][0], t, 0, 0, 0);
        t = __builtin_amdgcn_mfma_f32_16x16x32_bf16(ap[1], bv[dt][1], t, 0, 0, 0);
        o[nt][dt] = t;
      }
    }
  }
  __syncthreads();  // B2: v_s/p_s reads done; o_s (aliasing v_s) may be written
#pragma unroll
  for (int nt = 0; nt < 4; ++nt)
#pragma unroll
    for (int dt = 0; dt < 2; ++dt)
#pragma unroll
      for (int i = 0; i < 4; ++i)
        o_s[(nt * 16 + q * 4 + i) * 136 + w * 32 + dt * 16 + r] = f2b(o[nt][dt][i]);
  __syncthreads();  // B3: out2 visible

  // ====== P5: result = out2 @ proj_w^T + proj_b  (w hi/lo, 2-MFMA) ======
  {
    bf16x8 bph[2][4], bpl[2][4];
    float bias2[2];
#pragma unroll
    for (int c2 = 0; c2 < 2; ++c2) {
      int col = (w * 2 + c2) * 16 + r;
      bias2[c2] = projb[col];
#pragma unroll
      for (int ks = 0; ks < 4; ++ks) {
        f32x8 bp = ldf8(projw + col * 128 + ks * 32 + q * 8);
        split8(bp, &bph[c2][ks], &bpl[c2][ks]);
      }
    }
    float* ob = out + (size_t)b * 8192;
#pragma unroll
    for (int nt = 0; nt < 4; ++nt) {
      bf16x8 ao[4];
#pragma unroll
      for (int ks = 0; ks < 4; ++ks)
        ao[ks] = ldb16(o_s + (nt * 16 + r) * 136 + ks * 32 + q * 8);
#pragma unroll
      for (int c2 = 0; c2 < 2; ++c2) {
        f32x4 acc = zf;
#pragma unroll
        for (int ks = 0; ks < 4; ++ks) {
          acc = __builtin_amdgcn_mfma_f32_16x16x32_bf16(ao[ks], bph[c2][ks], acc, 0, 0, 0);
          acc = __builtin_amdgcn_mfma_f32_16x16x32_bf16(ao[ks], bpl[c2][ks], acc, 0, 0, 0);
        }
        int col = (w * 2 + c2) * 16 + r;
#pragma unroll
        for (int i = 0; i < 4; ++i)
          ob[(nt * 16 + q * 4 + i) * 128 + col] = acc[i] + bias2[c2];
      }
    }
  }
}

extern "C" void kernel_launch(void* const* d_in, const int* in_sizes, int n_in,
                              void* d_out, int out_size, void* d_ws, size_t ws_size,
                              hipStream_t stream) {
  (void)in_sizes; (void)n_in; (void)out_size; (void)d_ws; (void)ws_size;
  wattn<<<dim3(4096), dim3(256), 0, stream>>>(
      (const float*)d_in[0],  // x
      (const float*)d_in[1],  // y
      (const float*)d_in[2],  // P_thermal
      (const float*)d_in[3],  // mask
      (const float*)d_in[4],  // qkv_w
      (const float*)d_in[5],  // qkv_b
      (const float*)d_in[6],  // proj_w
      (const float*)d_in[7],  // proj_b
      (const float*)d_in[8],  // lambda_
      (float*)d_out);
}